// Round 2
// baseline (342.582 us; speedup 1.0000x reference)
//
#include <hip/hip_runtime.h>

#define S 28
#define BB 2
#define NC 80
#define MAXB 50
#define CH (BB*5+NC)   // 90

__device__ __constant__ float kCell = 1.0f / (float)S;

static constexpr float LAMBDA_COORD = 5.0f;
static constexpr float LAMBDA_NOOBJ = 0.1f;
static constexpr float EPS_IOU = 1e-6f;
static constexpr float EPSF    = 1e-7f;
static constexpr double PI_D   = 3.141592653589793;
static constexpr float FOUR_OVER_PI2 = (float)(4.0 / (PI_D * PI_D));

// ---------------- K1: build targets ----------------
// One thread per (batch, target). Winner per cell via u64 atomicMax on
// key = (float_bits(best_iou) << 32) | (MAXB - t).  key==0 <=> no object.
__global__ void build_targets_k(const float* __restrict__ pred,
                                const float* __restrict__ targ,
                                unsigned long long* __restrict__ keys,
                                unsigned int* __restrict__ clsmask,
                                float* __restrict__ tinfo,
                                int batch) {
    int idx = blockIdx.x * blockDim.x + threadIdx.x;
    if (idx >= batch * MAXB) return;
    int b = idx / MAXB;
    int t = idx - b * MAXB;

    const float* tg = targ + (size_t)idx * 5;
    float cls = tg[0];
    if (cls < 0.0f) return;  // invalid target: no state change
    float cx = tg[1], cy = tg[2], w = tg[3], h = tg[4];

    const float cell = kCell;
    float cxs = cx / cell;
    float cys = cy / cell;
    int col = min((int)cxs, S - 1);
    int row = min((int)cys, S - 1);
    float cx_rel = cxs - (float)col;
    float cy_rel = cys - (float)row;

    size_t cellidx = ((size_t)b * S + row) * S + col;
    const float* p = pred + cellidx * CH;

    // gt corners (absolute)
    float gx1 = cx - w * 0.5f, gy1 = cy - h * 0.5f;
    float gx2 = cx + w * 0.5f, gy2 = cy + h * 0.5f;

    float best = -1.0f;
    int bj = 0;
#pragma unroll
    for (int j = 0; j < BB; ++j) {
        float px = (p[j * 5 + 0] + (float)col) * cell;
        float py = (p[j * 5 + 1] + (float)row) * cell;
        float pw = p[j * 5 + 2];
        float ph = p[j * 5 + 3];
        float px1 = px - pw * 0.5f, py1 = py - ph * 0.5f;
        float px2 = px + pw * 0.5f, py2 = py + ph * 0.5f;
        float iw = fmaxf(fminf(px2, gx2) - fmaxf(px1, gx1), 0.0f);
        float ih = fmaxf(fminf(py2, gy2) - fmaxf(py1, gy1), 0.0f);
        float inter = iw * ih;
        float uni = fmaxf(px2 - px1, 0.0f) * fmaxf(py2 - py1, 0.0f)
                  + fmaxf(gx2 - gx1, 0.0f) * fmaxf(gy2 - gy1, 0.0f) - inter;
        float iou = inter / (uni + EPS_IOU);
        if (iou > best) { best = iou; bj = j; }  // strict >: first max wins (argmax)
    }

    int cid = (int)cls;
    cid = max(0, min(cid, NC - 1));
    atomicOr(&clsmask[cellidx * 3 + (cid >> 5)], 1u << (cid & 31));

    unsigned long long key =
        ((unsigned long long)__float_as_uint(best) << 32) |
        (unsigned long long)(unsigned)(MAXB - t);
    atomicMax(&keys[cellidx], key);

    float* ti = tinfo + (size_t)idx * 6;
    ti[0] = cx_rel; ti[1] = cy_rel; ti[2] = w; ti[3] = h;
    ti[4] = __int_as_float(bj);
}

// ---------------- K2: per-cell loss + reduction ----------------
__global__ void loss_k(const float* __restrict__ pred,
                       const unsigned long long* __restrict__ keys,
                       const unsigned int* __restrict__ clsmask,
                       const float* __restrict__ tinfo,
                       float* __restrict__ out,
                       int ncells, float inv_batch) {
    int cellidx = blockIdx.x * blockDim.x + threadIdx.x;
    float total = 0.0f;
    if (cellidx < ncells) {
        int b   = cellidx / (S * S);
        int rc  = cellidx - b * (S * S);
        int row = rc / S;
        int col = rc - row * S;
        const float cell = kCell;
        const float* p = pred + (size_t)cellidx * CH;

        // 10 box floats, 8B-aligned (cell stride 360B)
        float p0[10];
#pragma unroll
        for (int k = 0; k < 5; ++k) {
            float2 v = *(const float2*)(p + 2 * k);
            p0[2 * k] = v.x; p0[2 * k + 1] = v.y;
        }

        unsigned long long key = keys[cellidx];
        if (key != 0ull) {
            float best_iou = __uint_as_float((unsigned)(key >> 32));
            int t = MAXB - (int)(key & 0xffffffffu);
            const float* ti = tinfo + ((size_t)b * MAXB + t) * 6;
            float gcx_rel = ti[0], gcy_rel = ti[1], gw = ti[2], gh = ti[3];
            int resp = __float_as_int(ti[4]);

            float bx = p0[resp * 5 + 0], by = p0[resp * 5 + 1];
            float bw = p0[resp * 5 + 2], bh = p0[resp * 5 + 3];
            float conf_r = p0[resp * 5 + 4];
            float conf_o = p0[(1 - resp) * 5 + 4];

            float pax = (bx + (float)col) * cell;
            float pay = (by + (float)row) * cell;
            float paw = fabsf(bw), pah = fabsf(bh);
            float gax = (gcx_rel + (float)col) * cell;
            float gay = (gcy_rel + (float)row) * cell;

            // CIoU (EPS = 1e-7 here, unlike _iou)
            float px1 = pax - paw * 0.5f, py1 = pay - pah * 0.5f;
            float px2 = pax + paw * 0.5f, py2 = pay + pah * 0.5f;
            float gx1 = gax - gw * 0.5f,  gy1 = gay - gh * 0.5f;
            float gx2 = gax + gw * 0.5f,  gy2 = gay + gh * 0.5f;
            float iw = fmaxf(fminf(px2, gx2) - fmaxf(px1, gx1), 0.0f);
            float ih = fmaxf(fminf(py2, gy2) - fmaxf(py1, gy1), 0.0f);
            float inter = iw * ih;
            float area_p = fmaxf(px2 - px1, 0.0f) * fmaxf(py2 - py1, 0.0f);
            float area_g = fmaxf(gx2 - gx1, 0.0f) * fmaxf(gy2 - gy1, 0.0f);
            float uni = area_p + area_g - inter;
            float iou = inter / (uni + EPSF);
            float dx = pax - gax, dy = pay - gay;
            float rho2 = dx * dx + dy * dy;
            float cw = fmaxf(px2, gx2) - fminf(px1, gx1);
            float chh = fmaxf(py2, gy2) - fminf(py1, gy1);
            float c2 = cw * cw + chh * chh + EPSF;
            float dv = atanf(gw / (gh + EPSF)) - atanf(paw / (pah + EPSF));
            float v = FOUR_OVER_PI2 * dv * dv;
            float alpha = v / (1.0f - iou + v + EPSF);
            float ciou = 1.0f - iou + rho2 / c2 + alpha * v;

            total += LAMBDA_COORD * ciou;
            float d = conf_r - best_iou;
            total += d * d;
            total += LAMBDA_NOOBJ * conf_o * conf_o;  // only non-responsible box

            // class BCE (only obj cells contribute)
            unsigned m0 = clsmask[cellidx * 3 + 0];
            unsigned m1 = clsmask[cellidx * 3 + 1];
            unsigned m2 = clsmask[cellidx * 3 + 2];
            const float* pc = p + BB * 5;
            float cl = 0.0f;
#pragma unroll 8
            for (int k = 0; k < NC; ++k) {
                float x = pc[k];
                unsigned mw = (k < 32) ? m0 : (k < 64) ? m1 : m2;
                float gt = ((mw >> (k & 31)) & 1u) ? 1.0f : 0.0f;
                cl += fmaxf(x, 0.0f) - x * gt + log1pf(expf(-fabsf(x)));
            }
            total += cl;
        } else {
            total += LAMBDA_NOOBJ * (p0[4] * p0[4] + p0[9] * p0[9]);
        }
    }

    // block reduction: wave shuffle + LDS across waves
    float v = total;
#pragma unroll
    for (int off = 32; off > 0; off >>= 1)
        v += __shfl_down(v, off, 64);
    __shared__ float red[4];  // 256 threads / 64
    int lane = threadIdx.x & 63;
    int wid  = threadIdx.x >> 6;
    if (lane == 0) red[wid] = v;
    __syncthreads();
    if (threadIdx.x == 0) {
        float s = red[0] + red[1] + red[2] + red[3];
        atomicAdd(out, s * inv_batch);
    }
}

extern "C" void kernel_launch(void* const* d_in, const int* in_sizes, int n_in,
                              void* d_out, int out_size, void* d_ws, size_t ws_size,
                              hipStream_t stream) {
    const float* pred = (const float*)d_in[0];
    const float* targ = (const float*)d_in[1];
    int batch = in_sizes[0] / (S * S * CH);
    size_t ncells = (size_t)batch * S * S;

    // ws layout: keys (8B/cell) | clsmask (12B/cell) | tinfo (24B per (b,t))
    unsigned long long* keys = (unsigned long long*)d_ws;
    unsigned int* clsmask = (unsigned int*)((char*)d_ws + ncells * 8);
    float* tinfo = (float*)((char*)d_ws + ncells * 8 + ncells * 12);

    hipMemsetAsync(d_ws, 0, ncells * 8 + ncells * 12, stream);
    hipMemsetAsync(d_out, 0, sizeof(float) * out_size, stream);

    int nt = batch * MAXB;
    build_targets_k<<<(nt + 255) / 256, 256, 0, stream>>>(
        pred, targ, keys, clsmask, tinfo, batch);

    int total_cells = (int)ncells;
    loss_k<<<(total_cells + 255) / 256, 256, 0, stream>>>(
        pred, keys, clsmask, tinfo, (float*)d_out,
        total_cells, 1.0f / (float)batch);
}

// Round 3
// 263.940 us; speedup vs baseline: 1.2980x; 1.2980x over previous
//
#include <hip/hip_runtime.h>

#define S 28
#define BB 2
#define NC 80
#define MAXB 50
#define CH (BB*5+NC)   // 90

__device__ __constant__ float kCell = 1.0f / (float)S;

static constexpr float LAMBDA_COORD = 5.0f;
static constexpr float LAMBDA_NOOBJ = 0.1f;
static constexpr float EPS_IOU = 1e-6f;
static constexpr float EPSF    = 1e-7f;
static constexpr double PI_D   = 3.141592653589793;
static constexpr float FOUR_OVER_PI2 = (float)(4.0 / (PI_D * PI_D));

// ws layout: [0,16) obj count | keys 8B/cell | clsmask 12B/cell |
//            tinfo 24B/(b,t) | list 4B/(b,t)
// key = (float_bits(best_iou)<<32) | (MAXB - t);  key==0 <=> no object.

// ---------------- K1: build targets ----------------
__global__ void build_targets_k(const float* __restrict__ pred,
                                const float* __restrict__ targ,
                                unsigned long long* __restrict__ keys,
                                unsigned int* __restrict__ clsmask,
                                float* __restrict__ tinfo,
                                int batch) {
    int idx = blockIdx.x * blockDim.x + threadIdx.x;
    if (idx >= batch * MAXB) return;
    int b = idx / MAXB;
    int t = idx - b * MAXB;

    const float* tg = targ + (size_t)idx * 5;
    float cls = tg[0];
    if (cls < 0.0f) return;  // invalid target: no state change
    float cx = tg[1], cy = tg[2], w = tg[3], h = tg[4];

    const float cell = kCell;
    float cxs = cx / cell;
    float cys = cy / cell;
    int col = min((int)cxs, S - 1);
    int row = min((int)cys, S - 1);
    float cx_rel = cxs - (float)col;
    float cy_rel = cys - (float)row;

    size_t cellidx = ((size_t)b * S + row) * S + col;
    const float* p = pred + cellidx * CH;

    float gx1 = cx - w * 0.5f, gy1 = cy - h * 0.5f;
    float gx2 = cx + w * 0.5f, gy2 = cy + h * 0.5f;

    float best = -1.0f;
    int bj = 0;
#pragma unroll
    for (int j = 0; j < BB; ++j) {
        float px = (p[j * 5 + 0] + (float)col) * cell;
        float py = (p[j * 5 + 1] + (float)row) * cell;
        float pw = p[j * 5 + 2];
        float ph = p[j * 5 + 3];
        float px1 = px - pw * 0.5f, py1 = py - ph * 0.5f;
        float px2 = px + pw * 0.5f, py2 = py + ph * 0.5f;
        float iw = fmaxf(fminf(px2, gx2) - fmaxf(px1, gx1), 0.0f);
        float ih = fmaxf(fminf(py2, gy2) - fmaxf(py1, gy1), 0.0f);
        float inter = iw * ih;
        float uni = fmaxf(px2 - px1, 0.0f) * fmaxf(py2 - py1, 0.0f)
                  + fmaxf(gx2 - gx1, 0.0f) * fmaxf(gy2 - gy1, 0.0f) - inter;
        float iou = inter / (uni + EPS_IOU);
        if (iou > best) { best = iou; bj = j; }  // strict >: first max wins
    }

    int cid = (int)cls;
    cid = max(0, min(cid, NC - 1));
    atomicOr(&clsmask[cellidx * 3 + (cid >> 5)], 1u << (cid & 31));

    unsigned long long key =
        ((unsigned long long)__float_as_uint(best) << 32) |
        (unsigned long long)(unsigned)(MAXB - t);
    atomicMax(&keys[cellidx], key);

    float* ti = tinfo + (size_t)idx * 6;
    ti[0] = cx_rel; ti[1] = cy_rel; ti[2] = w; ti[3] = h;
    ti[4] = __int_as_float(bj);
}

// ---------------- K2: uniform conf^2 stream + obj-cell compaction ----------
// Mask-free: every cell contributes LAMBDA_NOOBJ*(c0^2+c1^2); the obj kernel
// subtracts the responsible box's term. Also appends obj cells to the list.
__global__ void conf_pass_k(const float* __restrict__ pred,
                            const unsigned long long* __restrict__ keys,
                            unsigned int* __restrict__ count,
                            int* __restrict__ list,
                            float* __restrict__ out,
                            int ncells, float inv_batch) {
    int i = blockIdx.x * blockDim.x + threadIdx.x;
    float tot = 0.0f;
    if (i < ncells) {
        const float* p = pred + (size_t)i * CH;
        float c0 = p[4];
        float c1 = p[9];
        tot = LAMBDA_NOOBJ * (c0 * c0 + c1 * c1);
        if (keys[i] != 0ull) {
            unsigned pos = atomicAdd(count, 1u);
            list[pos] = i;
        }
    }
    // block reduction
    float v = tot;
#pragma unroll
    for (int off = 32; off > 0; off >>= 1)
        v += __shfl_down(v, off, 64);
    __shared__ float red[4];
    int lane = threadIdx.x & 63;
    int wid  = threadIdx.x >> 6;
    if (lane == 0) red[wid] = v;
    __syncthreads();
    if (threadIdx.x == 0)
        atomicAdd(out, (red[0] + red[1] + red[2] + red[3]) * inv_batch);
}

// ---------------- K3: obj-cell loss (16 lanes per cell) ----------------
#define GROUPS_PER_BLOCK 16   // 256 threads / 16 lanes
__global__ void obj_loss_k(const float* __restrict__ pred,
                           const unsigned long long* __restrict__ keys,
                           const unsigned int* __restrict__ clsmask,
                           const float* __restrict__ tinfo,
                           const unsigned int* __restrict__ count,
                           const int* __restrict__ list,
                           float* __restrict__ out, float inv_batch) {
    unsigned n = *count;
    if (blockIdx.x * GROUPS_PER_BLOCK >= n) return;  // block-uniform early out

    int gid    = (blockIdx.x * blockDim.x + threadIdx.x) >> 4;
    int lane16 = threadIdx.x & 15;
    float tot = 0.0f;

    if ((unsigned)gid < n) {
        int cellidx = list[gid];
        const float* p = pred + (size_t)cellidx * CH;

        // class BCE: lane l handles classes l, l+16, l+32, l+48, l+64
        unsigned m0 = clsmask[(size_t)cellidx * 3 + 0];
        unsigned m1 = clsmask[(size_t)cellidx * 3 + 1];
        unsigned m2 = clsmask[(size_t)cellidx * 3 + 2];
        const float* pc = p + BB * 5;
        float cl = 0.0f;
#pragma unroll
        for (int j = 0; j < 5; ++j) {
            int k = lane16 + 16 * j;
            float x = pc[k];
            unsigned mw = (k < 32) ? m0 : (k < 64) ? m1 : m2;
            float gt = ((mw >> (k & 31)) & 1u) ? 1.0f : 0.0f;
            cl += fmaxf(x, 0.0f) - x * gt + log1pf(expf(-fabsf(x)));
        }
        // reduce cl across the 16-lane group
#pragma unroll
        for (int off = 1; off < 16; off <<= 1)
            cl += __shfl_xor(cl, off, 64);

        if (lane16 == 0) {
            int b   = cellidx / (S * S);
            int rc  = cellidx - b * (S * S);
            int row = rc / S;
            int col = rc - row * S;
            const float cell = kCell;

            unsigned long long key = keys[cellidx];
            float best_iou = __uint_as_float((unsigned)(key >> 32));
            int t = MAXB - (int)(key & 0xffffffffu);
            const float* ti = tinfo + ((size_t)b * MAXB + t) * 6;
            float gcx_rel = ti[0], gcy_rel = ti[1], gw = ti[2], gh = ti[3];
            int resp = __float_as_int(ti[4]);

            float p0[10];
#pragma unroll
            for (int k = 0; k < 5; ++k) {
                float2 v2 = *(const float2*)(p + 2 * k);
                p0[2 * k] = v2.x; p0[2 * k + 1] = v2.y;
            }
            float bx = p0[resp * 5 + 0], by = p0[resp * 5 + 1];
            float bw = p0[resp * 5 + 2], bh = p0[resp * 5 + 3];
            float conf_r = p0[resp * 5 + 4];

            float pax = (bx + (float)col) * cell;
            float pay = (by + (float)row) * cell;
            float paw = fabsf(bw), pah = fabsf(bh);
            float gax = (gcx_rel + (float)col) * cell;
            float gay = (gcy_rel + (float)row) * cell;

            float px1 = pax - paw * 0.5f, py1 = pay - pah * 0.5f;
            float px2 = pax + paw * 0.5f, py2 = pay + pah * 0.5f;
            float gx1 = gax - gw * 0.5f,  gy1 = gay - gh * 0.5f;
            float gx2 = gax + gw * 0.5f,  gy2 = gay + gh * 0.5f;
            float iw = fmaxf(fminf(px2, gx2) - fmaxf(px1, gx1), 0.0f);
            float ih = fmaxf(fminf(py2, gy2) - fmaxf(py1, gy1), 0.0f);
            float inter = iw * ih;
            float area_p = fmaxf(px2 - px1, 0.0f) * fmaxf(py2 - py1, 0.0f);
            float area_g = fmaxf(gx2 - gx1, 0.0f) * fmaxf(gy2 - gy1, 0.0f);
            float uni = area_p + area_g - inter;
            float iou = inter / (uni + EPSF);
            float dx = pax - gax, dy = pay - gay;
            float rho2 = dx * dx + dy * dy;
            float cw = fmaxf(px2, gx2) - fminf(px1, gx1);
            float chh = fmaxf(py2, gy2) - fminf(py1, gy1);
            float c2 = cw * cw + chh * chh + EPSF;
            float dv = atanf(gw / (gh + EPSF)) - atanf(paw / (pah + EPSF));
            float v = FOUR_OVER_PI2 * dv * dv;
            float alpha = v / (1.0f - iou + v + EPSF);
            float ciou = 1.0f - iou + rho2 / c2 + alpha * v;

            float d = conf_r - best_iou;
            tot = cl + LAMBDA_COORD * ciou + d * d
                - LAMBDA_NOOBJ * conf_r * conf_r;  // undo conf_pass's term
        }
    }

    float v = tot;
#pragma unroll
    for (int off = 32; off > 0; off >>= 1)
        v += __shfl_down(v, off, 64);
    __shared__ float red[4];
    int lane = threadIdx.x & 63;
    int wid  = threadIdx.x >> 6;
    if (lane == 0) red[wid] = v;
    __syncthreads();
    if (threadIdx.x == 0)
        atomicAdd(out, (red[0] + red[1] + red[2] + red[3]) * inv_batch);
}

extern "C" void kernel_launch(void* const* d_in, const int* in_sizes, int n_in,
                              void* d_out, int out_size, void* d_ws, size_t ws_size,
                              hipStream_t stream) {
    const float* pred = (const float*)d_in[0];
    const float* targ = (const float*)d_in[1];
    int batch = in_sizes[0] / (S * S * CH);
    size_t ncells = (size_t)batch * S * S;
    int nt = batch * MAXB;

    char* ws = (char*)d_ws;
    unsigned int* count = (unsigned int*)ws;                       // 16 B
    unsigned long long* keys = (unsigned long long*)(ws + 16);     // 8*ncells
    unsigned int* clsmask = (unsigned int*)(ws + 16 + ncells * 8); // 12*ncells
    float* tinfo = (float*)(ws + 16 + ncells * 20);                // 24*nt
    int* list = (int*)(ws + 16 + ncells * 20 + (size_t)nt * 24);   // 4*nt

    hipMemsetAsync(d_ws, 0, 16 + ncells * 20, stream);
    hipMemsetAsync(d_out, 0, sizeof(float) * out_size, stream);

    build_targets_k<<<(nt + 255) / 256, 256, 0, stream>>>(
        pred, targ, keys, clsmask, tinfo, batch);

    int total_cells = (int)ncells;
    float inv_batch = 1.0f / (float)batch;
    conf_pass_k<<<(total_cells + 255) / 256, 256, 0, stream>>>(
        pred, keys, count, list, (float*)d_out, total_cells, inv_batch);

    int nblocks_obj = (nt + GROUPS_PER_BLOCK - 1) / GROUPS_PER_BLOCK;
    obj_loss_k<<<nblocks_obj, 256, 0, stream>>>(
        pred, keys, clsmask, tinfo, count, list, (float*)d_out, inv_batch);
}

// Round 4
// 218.688 us; speedup vs baseline: 1.5665x; 1.2069x over previous
//
#include <hip/hip_runtime.h>

#define S 28
#define BB 2
#define NC 80
#define MAXB 50
#define CH (BB*5+NC)   // 90

__device__ __constant__ float kCell = 1.0f / (float)S;

static constexpr float LAMBDA_COORD = 5.0f;
static constexpr float LAMBDA_NOOBJ = 0.1f;
static constexpr float EPS_IOU = 1e-6f;
static constexpr float EPSF    = 1e-7f;
static constexpr double PI_D   = 3.141592653589793;
static constexpr float FOUR_OVER_PI2 = (float)(4.0 / (PI_D * PI_D));

// ws layout: keys 8B/cell | clsmask 12B/cell
// key = (float_bits(best_iou)<<32) | (MAXB - t);  key==0 <=> no object.
// Winner recovery: group (b,t) is responsible iff low32(keys[cell]) == MAXB-t.

// ---------------- K1: build targets (atomics only, no tinfo) ----------------
__global__ void build_targets_k(const float* __restrict__ pred,
                                const float* __restrict__ targ,
                                unsigned long long* __restrict__ keys,
                                unsigned int* __restrict__ clsmask,
                                int batch) {
    int idx = blockIdx.x * blockDim.x + threadIdx.x;
    if (idx >= batch * MAXB) return;
    int b = idx / MAXB;
    int t = idx - b * MAXB;

    const float* tg = targ + (size_t)idx * 5;
    float cls = tg[0];
    if (cls < 0.0f) return;  // invalid target: no state change
    float cx = tg[1], cy = tg[2], w = tg[3], h = tg[4];

    const float cell = kCell;
    int col = min((int)(cx / cell), S - 1);
    int row = min((int)(cy / cell), S - 1);

    size_t cellidx = ((size_t)b * S + row) * S + col;
    const float* p = pred + cellidx * CH;

    float gx1 = cx - w * 0.5f, gy1 = cy - h * 0.5f;
    float gx2 = cx + w * 0.5f, gy2 = cy + h * 0.5f;

    float best = -1.0f;
#pragma unroll
    for (int j = 0; j < BB; ++j) {
        float px = (p[j * 5 + 0] + (float)col) * cell;
        float py = (p[j * 5 + 1] + (float)row) * cell;
        float pw = p[j * 5 + 2];
        float ph = p[j * 5 + 3];
        float px1 = px - pw * 0.5f, py1 = py - ph * 0.5f;
        float px2 = px + pw * 0.5f, py2 = py + ph * 0.5f;
        float iw = fmaxf(fminf(px2, gx2) - fmaxf(px1, gx1), 0.0f);
        float ih = fmaxf(fminf(py2, gy2) - fmaxf(py1, gy1), 0.0f);
        float inter = iw * ih;
        float uni = fmaxf(px2 - px1, 0.0f) * fmaxf(py2 - py1, 0.0f)
                  + fmaxf(gx2 - gx1, 0.0f) * fmaxf(gy2 - gy1, 0.0f) - inter;
        float iou = inter / (uni + EPS_IOU);
        best = fmaxf(best, iou);
    }

    int cid = (int)cls;
    cid = max(0, min(cid, NC - 1));
    atomicOr(&clsmask[cellidx * 3 + (cid >> 5)], 1u << (cid & 31));

    unsigned long long key =
        ((unsigned long long)__float_as_uint(best) << 32) |
        (unsigned long long)(unsigned)(MAXB - t);
    atomicMax(&keys[cellidx], key);
}

// ---------------- K2: fused conf^2 stream + winner-target loss ----------------
// Thread tid: conf^2 for cell tid (if < ncells).  16-lane group g=(tid>>4):
// target (b,t)=g; winner iff low32(keys[cell]) == MAXB-t; then parallel BCE
// (5 classes per lane, coalesced) + lane-0 CIoU/conf terms.
__global__ void fused_loss_k(const float* __restrict__ pred,
                             const float* __restrict__ targ,
                             const unsigned long long* __restrict__ keys,
                             const unsigned int* __restrict__ clsmask,
                             float* __restrict__ out,
                             int batch, float inv_batch) {
    int tid = blockIdx.x * blockDim.x + threadIdx.x;
    int ncells = batch * S * S;
    int nt = batch * MAXB;
    float tot = 0.0f;

    // --- branchless noobj conf stream (every cell, both boxes) ---
    if (tid < ncells) {
        const float* p = pred + (size_t)tid * CH;
        float c0 = p[4];
        float c1 = p[9];
        tot = LAMBDA_NOOBJ * (c0 * c0 + c1 * c1);
    }

    // --- per-target group work ---
    int gid    = tid >> 4;
    int lane16 = tid & 15;
    if (gid < nt) {
        int b = gid / MAXB;
        int t = gid - b * MAXB;
        const float* tg = targ + (size_t)gid * 5;
        float cls = tg[0];
        if (cls >= 0.0f) {  // uniform across the 16-lane group
            float cx = tg[1], cy = tg[2], gw = tg[3], gh = tg[4];
            const float cell = kCell;
            float cxs = cx / cell;
            float cys = cy / cell;
            int col = min((int)cxs, S - 1);
            int row = min((int)cys, S - 1);
            size_t cellidx = ((size_t)b * S + row) * S + col;

            unsigned long long key = keys[cellidx];
            if ((int)(unsigned)(key & 0xffffffffu) == MAXB - t) {  // winner
                const float* p = pred + cellidx * CH;

                // class BCE: lane l -> classes l, l+16, ..., l+64 (coalesced)
                unsigned m0 = clsmask[cellidx * 3 + 0];
                unsigned m1 = clsmask[cellidx * 3 + 1];
                unsigned m2 = clsmask[cellidx * 3 + 2];
                const float* pc = p + BB * 5;
                float cl = 0.0f;
#pragma unroll
                for (int j = 0; j < 5; ++j) {
                    int k = lane16 + 16 * j;
                    float x = pc[k];
                    unsigned mw = (k < 32) ? m0 : (k < 64) ? m1 : m2;
                    float gt = ((mw >> (k & 31)) & 1u) ? 1.0f : 0.0f;
                    cl += fmaxf(x, 0.0f) - x * gt + log1pf(expf(-fabsf(x)));
                }
#pragma unroll
                for (int off = 1; off < 16; off <<= 1)
                    cl += __shfl_xor(cl, off, 64);

                if (lane16 == 0) {
                    float best_iou = __uint_as_float((unsigned)(key >> 32));
                    float cx_rel = cxs - (float)col;
                    float cy_rel = cys - (float)row;

                    float p0[10];
#pragma unroll
                    for (int k = 0; k < 5; ++k) {
                        float2 v2 = *(const float2*)(p + 2 * k);
                        p0[2 * k] = v2.x; p0[2 * k + 1] = v2.y;
                    }

                    // replay K1's argmax exactly (bit-identical) to get resp
                    float gax1 = cx - gw * 0.5f, gay1 = cy - gh * 0.5f;
                    float gax2 = cx + gw * 0.5f, gay2 = cy + gh * 0.5f;
                    float bst = -1.0f; int resp = 0;
#pragma unroll
                    for (int j = 0; j < BB; ++j) {
                        float px = (p0[j * 5 + 0] + (float)col) * cell;
                        float py = (p0[j * 5 + 1] + (float)row) * cell;
                        float pw = p0[j * 5 + 2];
                        float ph = p0[j * 5 + 3];
                        float px1 = px - pw * 0.5f, py1 = py - ph * 0.5f;
                        float px2 = px + pw * 0.5f, py2 = py + ph * 0.5f;
                        float iw = fmaxf(fminf(px2, gax2) - fmaxf(px1, gax1), 0.0f);
                        float ih = fmaxf(fminf(py2, gay2) - fmaxf(py1, gay1), 0.0f);
                        float inter = iw * ih;
                        float uni = fmaxf(px2 - px1, 0.0f) * fmaxf(py2 - py1, 0.0f)
                                  + fmaxf(gax2 - gax1, 0.0f) * fmaxf(gay2 - gay1, 0.0f) - inter;
                        float iou = inter / (uni + EPS_IOU);
                        if (iou > bst) { bst = iou; resp = j; }
                    }

                    float bx = p0[resp * 5 + 0], by = p0[resp * 5 + 1];
                    float bw = p0[resp * 5 + 2], bh = p0[resp * 5 + 3];
                    float conf_r = p0[resp * 5 + 4];

                    float pax = (bx + (float)col) * cell;
                    float pay = (by + (float)row) * cell;
                    float paw = fabsf(bw), pah = fabsf(bh);
                    float gax = (cx_rel + (float)col) * cell;
                    float gay = (cy_rel + (float)row) * cell;

                    // CIoU (EPS = 1e-7 here)
                    float px1 = pax - paw * 0.5f, py1 = pay - pah * 0.5f;
                    float px2 = pax + paw * 0.5f, py2 = pay + pah * 0.5f;
                    float gx1 = gax - gw * 0.5f,  gy1 = gay - gh * 0.5f;
                    float gx2 = gax + gw * 0.5f,  gy2 = gay + gh * 0.5f;
                    float iw = fmaxf(fminf(px2, gx2) - fmaxf(px1, gx1), 0.0f);
                    float ih = fmaxf(fminf(py2, gy2) - fmaxf(py1, gy1), 0.0f);
                    float inter = iw * ih;
                    float area_p = fmaxf(px2 - px1, 0.0f) * fmaxf(py2 - py1, 0.0f);
                    float area_g = fmaxf(gx2 - gx1, 0.0f) * fmaxf(gy2 - gy1, 0.0f);
                    float uni = area_p + area_g - inter;
                    float iou = inter / (uni + EPSF);
                    float dx = pax - gax, dy = pay - gay;
                    float rho2 = dx * dx + dy * dy;
                    float cw = fmaxf(px2, gx2) - fminf(px1, gx1);
                    float chh = fmaxf(py2, gy2) - fminf(py1, gy1);
                    float c2 = cw * cw + chh * chh + EPSF;
                    float dv = atanf(gw / (gh + EPSF)) - atanf(paw / (pah + EPSF));
                    float v = FOUR_OVER_PI2 * dv * dv;
                    float alpha = v / (1.0f - iou + v + EPSF);
                    float ciou = 1.0f - iou + rho2 / c2 + alpha * v;

                    float d = conf_r - best_iou;
                    tot += cl + LAMBDA_COORD * ciou + d * d
                         - LAMBDA_NOOBJ * conf_r * conf_r;  // undo stream term
                }
            }
        }
    }

    // block reduction: wave shuffle + LDS across waves, 1 atomic per block
    float v = tot;
#pragma unroll
    for (int off = 32; off > 0; off >>= 1)
        v += __shfl_down(v, off, 64);
    __shared__ float red[4];
    int lane = threadIdx.x & 63;
    int wid  = threadIdx.x >> 6;
    if (lane == 0) red[wid] = v;
    __syncthreads();
    if (threadIdx.x == 0)
        atomicAdd(out, (red[0] + red[1] + red[2] + red[3]) * inv_batch);
}

extern "C" void kernel_launch(void* const* d_in, const int* in_sizes, int n_in,
                              void* d_out, int out_size, void* d_ws, size_t ws_size,
                              hipStream_t stream) {
    const float* pred = (const float*)d_in[0];
    const float* targ = (const float*)d_in[1];
    int batch = in_sizes[0] / (S * S * CH);
    size_t ncells = (size_t)batch * S * S;
    int nt = batch * MAXB;

    char* ws = (char*)d_ws;
    unsigned long long* keys = (unsigned long long*)ws;       // 8*ncells
    unsigned int* clsmask = (unsigned int*)(ws + ncells * 8); // 12*ncells

    hipMemsetAsync(d_ws, 0, ncells * 20, stream);
    hipMemsetAsync(d_out, 0, sizeof(float) * out_size, stream);

    build_targets_k<<<(nt + 255) / 256, 256, 0, stream>>>(
        pred, targ, keys, clsmask, batch);

    // grid covers max(ncells, 16*nt); 16*nt >= ncells since 16*MAXB=800 >= S*S=784
    int nthreads = 16 * nt;
    if (nthreads < (int)ncells) nthreads = (int)ncells;
    fused_loss_k<<<(nthreads + 255) / 256, 256, 0, stream>>>(
        pred, targ, keys, clsmask, (float*)d_out, batch, 1.0f / (float)batch);
}

// Round 5
// 203.450 us; speedup vs baseline: 1.6839x; 1.0749x over previous
//
#include <hip/hip_runtime.h>

#define S 28
#define BB 2
#define NC 80
#define MAXB 50
#define CH (BB*5+NC)   // 90
#define BLOCK 256

__device__ __constant__ float kCell = 1.0f / (float)S;

static constexpr float LAMBDA_COORD = 5.0f;
static constexpr float LAMBDA_NOOBJ = 0.1f;
static constexpr float EPS_IOU = 1e-6f;
static constexpr float EPSF    = 1e-7f;
static constexpr double PI_D   = 3.141592653589793;
static constexpr float FOUR_OVER_PI2 = (float)(4.0 / (PI_D * PI_D));

// Single fused kernel. Thread tid: branchless noobj conf^2 for cell tid.
// 16-lane group gid = (b,t): scan the image's 50 targets (lane-strided),
// filter to same cell, compute each candidate's best-IoU (bit-identical
// f32 replay), reduce winner key + class-bit union in-registers.
// Winner group (low32(key) == MAXB-t) adds BCE + CIoU + conf terms.
// No global atomics, no precomputed state. Block sums -> partial[block].
__global__ void __launch_bounds__(BLOCK)
yolo_loss_k(const float* __restrict__ pred,
            const float* __restrict__ targ,
            float* __restrict__ partial,
            int batch) {
    int tid = blockIdx.x * BLOCK + threadIdx.x;
    int ncells = batch * S * S;
    int nt = batch * MAXB;
    float tot = 0.0f;
    const float cell = kCell;

    // --- branchless noobj conf stream (every cell, both boxes) ---
    if (tid < ncells) {
        const float* p = pred + (size_t)tid * CH;
        float c0 = p[4];
        float c1 = p[9];
        tot = LAMBDA_NOOBJ * (c0 * c0 + c1 * c1);
    }

    // --- per-target group work ---
    int gid    = tid >> 4;
    int lane16 = tid & 15;
    if (gid < nt) {
        int b = gid / MAXB;
        int t = gid - b * MAXB;
        const float* tg = targ + (size_t)gid * 5;
        float cls = tg[0];
        if (cls >= 0.0f) {  // uniform across the 16-lane group
            float cx = tg[1], cy = tg[2], gw = tg[3], gh = tg[4];
            float cxs = cx / cell;
            float cys = cy / cell;
            int col = min((int)cxs, S - 1);
            int row = min((int)cys, S - 1);
            size_t cellidx = ((size_t)b * S + row) * S + col;
            const float* p = pred + cellidx * CH;

            // ---- local winner scan over this image's targets ----
            const float* timg = targ + (size_t)b * MAXB * 5;
            unsigned long long bestkey = 0ull;
            unsigned m0 = 0, m1 = 0, m2 = 0;
            for (int tt = lane16; tt < MAXB; tt += 16) {
                const float* tg2 = timg + tt * 5;
                float c2 = tg2[0];
                if (c2 < 0.0f) continue;
                float cx2 = tg2[1], cy2 = tg2[2], w2 = tg2[3], h2 = tg2[4];
                int col2 = min((int)(cx2 / cell), S - 1);
                int row2 = min((int)(cy2 / cell), S - 1);
                if (col2 != col || row2 != row) continue;
                int cid = max(0, min((int)c2, NC - 1));
                if (cid < 32)      m0 |= 1u << cid;
                else if (cid < 64) m1 |= 1u << (cid - 32);
                else               m2 |= 1u << (cid - 64);
                // best-IoU of the cell's 2 pred boxes vs this gt (exact replay)
                float gx1 = cx2 - w2 * 0.5f, gy1 = cy2 - h2 * 0.5f;
                float gx2 = cx2 + w2 * 0.5f, gy2 = cy2 + h2 * 0.5f;
                float best = -1.0f;
#pragma unroll
                for (int j = 0; j < BB; ++j) {
                    float px = (p[j * 5 + 0] + (float)col) * cell;
                    float py = (p[j * 5 + 1] + (float)row) * cell;
                    float pw = p[j * 5 + 2];
                    float ph = p[j * 5 + 3];
                    float px1 = px - pw * 0.5f, py1 = py - ph * 0.5f;
                    float px2 = px + pw * 0.5f, py2 = py + ph * 0.5f;
                    float iw = fmaxf(fminf(px2, gx2) - fmaxf(px1, gx1), 0.0f);
                    float ih = fmaxf(fminf(py2, gy2) - fmaxf(py1, gy1), 0.0f);
                    float inter = iw * ih;
                    float uni = fmaxf(px2 - px1, 0.0f) * fmaxf(py2 - py1, 0.0f)
                              + fmaxf(gx2 - gx1, 0.0f) * fmaxf(gy2 - gy1, 0.0f) - inter;
                    float iou = inter / (uni + EPS_IOU);
                    best = fmaxf(best, iou);
                }
                unsigned long long key =
                    ((unsigned long long)__float_as_uint(best) << 32) |
                    (unsigned long long)(unsigned)(MAXB - tt);
                if (key > bestkey) bestkey = key;
            }
            // in-group reduction (xor masks <16 stay within the 16-lane group)
#pragma unroll
            for (int off = 1; off < 16; off <<= 1) {
                unsigned long long ok = __shfl_xor(bestkey, off, 64);
                if (ok > bestkey) bestkey = ok;
                m0 |= __shfl_xor(m0, off, 64);
                m1 |= __shfl_xor(m1, off, 64);
                m2 |= __shfl_xor(m2, off, 64);
            }

            if ((unsigned)(bestkey & 0xffffffffu) == (unsigned)(MAXB - t)) {
                // this group's target owns the cell
                // class BCE: lane l -> classes l, l+16, ..., l+64 (coalesced)
                const float* pc = p + BB * 5;
                float cl = 0.0f;
#pragma unroll
                for (int j = 0; j < 5; ++j) {
                    int k = lane16 + 16 * j;
                    float x = pc[k];
                    unsigned mw = (k < 32) ? m0 : (k < 64) ? m1 : m2;
                    float gt = ((mw >> (k & 31)) & 1u) ? 1.0f : 0.0f;
                    cl += fmaxf(x, 0.0f) - x * gt + log1pf(expf(-fabsf(x)));
                }
#pragma unroll
                for (int off = 1; off < 16; off <<= 1)
                    cl += __shfl_xor(cl, off, 64);

                if (lane16 == 0) {
                    float best_iou = __uint_as_float((unsigned)(bestkey >> 32));
                    float cx_rel = cxs - (float)col;
                    float cy_rel = cys - (float)row;

                    float p0[10];
#pragma unroll
                    for (int k = 0; k < 5; ++k) {
                        float2 v2 = *(const float2*)(p + 2 * k);
                        p0[2 * k] = v2.x; p0[2 * k + 1] = v2.y;
                    }

                    // replay my own argmax to get resp (bit-identical)
                    float gax1 = cx - gw * 0.5f, gay1 = cy - gh * 0.5f;
                    float gax2 = cx + gw * 0.5f, gay2 = cy + gh * 0.5f;
                    float bst = -1.0f; int resp = 0;
#pragma unroll
                    for (int j = 0; j < BB; ++j) {
                        float px = (p0[j * 5 + 0] + (float)col) * cell;
                        float py = (p0[j * 5 + 1] + (float)row) * cell;
                        float pw = p0[j * 5 + 2];
                        float ph = p0[j * 5 + 3];
                        float px1 = px - pw * 0.5f, py1 = py - ph * 0.5f;
                        float px2 = px + pw * 0.5f, py2 = py + ph * 0.5f;
                        float iw = fmaxf(fminf(px2, gax2) - fmaxf(px1, gax1), 0.0f);
                        float ih = fmaxf(fminf(py2, gay2) - fmaxf(py1, gay1), 0.0f);
                        float inter = iw * ih;
                        float uni = fmaxf(px2 - px1, 0.0f) * fmaxf(py2 - py1, 0.0f)
                                  + fmaxf(gax2 - gax1, 0.0f) * fmaxf(gay2 - gay1, 0.0f) - inter;
                        float iou = inter / (uni + EPS_IOU);
                        if (iou > bst) { bst = iou; resp = j; }
                    }

                    float bx = p0[resp * 5 + 0], by = p0[resp * 5 + 1];
                    float bw = p0[resp * 5 + 2], bh = p0[resp * 5 + 3];
                    float conf_r = p0[resp * 5 + 4];

                    float pax = (bx + (float)col) * cell;
                    float pay = (by + (float)row) * cell;
                    float paw = fabsf(bw), pah = fabsf(bh);
                    float gax = (cx_rel + (float)col) * cell;
                    float gay = (cy_rel + (float)row) * cell;

                    // CIoU (EPS = 1e-7 here)
                    float px1 = pax - paw * 0.5f, py1 = pay - pah * 0.5f;
                    float px2 = pax + paw * 0.5f, py2 = pay + pah * 0.5f;
                    float gx1 = gax - gw * 0.5f,  gy1 = gay - gh * 0.5f;
                    float gx2 = gax + gw * 0.5f,  gy2 = gay + gh * 0.5f;
                    float iw = fmaxf(fminf(px2, gx2) - fmaxf(px1, gx1), 0.0f);
                    float ih = fmaxf(fminf(py2, gy2) - fmaxf(py1, gy1), 0.0f);
                    float inter = iw * ih;
                    float area_p = fmaxf(px2 - px1, 0.0f) * fmaxf(py2 - py1, 0.0f);
                    float area_g = fmaxf(gx2 - gx1, 0.0f) * fmaxf(gy2 - gy1, 0.0f);
                    float uni = area_p + area_g - inter;
                    float iou = inter / (uni + EPSF);
                    float dx = pax - gax, dy = pay - gay;
                    float rho2 = dx * dx + dy * dy;
                    float cw = fmaxf(px2, gx2) - fminf(px1, gx1);
                    float chh = fmaxf(py2, gy2) - fminf(py1, gy1);
                    float c2 = cw * cw + chh * chh + EPSF;
                    float dv = atanf(gw / (gh + EPSF)) - atanf(paw / (pah + EPSF));
                    float v = FOUR_OVER_PI2 * dv * dv;
                    float alpha = v / (1.0f - iou + v + EPSF);
                    float ciou = 1.0f - iou + rho2 / c2 + alpha * v;

                    float d = conf_r - best_iou;
                    tot += cl + LAMBDA_COORD * ciou + d * d
                         - LAMBDA_NOOBJ * conf_r * conf_r;  // undo stream term
                }
            }
        }
    }

    // block reduction -> partial[block] (no atomics)
    float v = tot;
#pragma unroll
    for (int off = 32; off > 0; off >>= 1)
        v += __shfl_down(v, off, 64);
    __shared__ float red[4];
    int lane = threadIdx.x & 63;
    int wid  = threadIdx.x >> 6;
    if (lane == 0) red[wid] = v;
    __syncthreads();
    if (threadIdx.x == 0)
        partial[blockIdx.x] = red[0] + red[1] + red[2] + red[3];
}

// Final reduction: one block sums the partials and writes out[0].
__global__ void __launch_bounds__(BLOCK)
reduce_k(const float* __restrict__ partial, float* __restrict__ out,
         int n, float inv_batch) {
    float s = 0.0f;
    for (int i = threadIdx.x; i < n; i += BLOCK)
        s += partial[i];
#pragma unroll
    for (int off = 32; off > 0; off >>= 1)
        s += __shfl_down(s, off, 64);
    __shared__ float red[4];
    int lane = threadIdx.x & 63;
    int wid  = threadIdx.x >> 6;
    if (lane == 0) red[wid] = s;
    __syncthreads();
    if (threadIdx.x == 0)
        out[0] = (red[0] + red[1] + red[2] + red[3]) * inv_batch;
}

extern "C" void kernel_launch(void* const* d_in, const int* in_sizes, int n_in,
                              void* d_out, int out_size, void* d_ws, size_t ws_size,
                              hipStream_t stream) {
    const float* pred = (const float*)d_in[0];
    const float* targ = (const float*)d_in[1];
    int batch = in_sizes[0] / (S * S * CH);
    size_t ncells = (size_t)batch * S * S;
    int nt = batch * MAXB;

    // grid covers max(ncells, 16*nt); 16*MAXB=800 >= S*S=784 so 16*nt wins
    int nthreads = 16 * nt;
    if (nthreads < (int)ncells) nthreads = (int)ncells;
    int nblocks = (nthreads + BLOCK - 1) / BLOCK;

    float* partial = (float*)d_ws;  // nblocks floats; written before read

    yolo_loss_k<<<nblocks, BLOCK, 0, stream>>>(pred, targ, partial, batch);
    reduce_k<<<1, BLOCK, 0, stream>>>(partial, (float*)d_out, nblocks,
                                      1.0f / (float)batch);
}